// Round 3
// baseline (212.182 us; speedup 1.0000x reference)
//
#include <hip/hip_runtime.h>
#include <stdint.h>
#include <math.h>

// ---------------------------------------------------------------------------
// XNOR-Net forward: 3 binarized stride-2 convs + global avg pool + binary FC.
// Exact integer popcount dots; sign decisions via exact integer thresholds.
// Ledger: ~85us fixed harness work (268MB ws re-poison fills at ~43us each,
// 78% HBM peak = their roofline); fill variance => run noise ~±5us.
// R9=142.8, R10=151.0 (FAILED: scalar stores), R11=144.5 (recovered).
// K1 conv compute proven off-critical-path (3 structural rewrites neutral).
// R12: (a) K3 fast-path: per-channel integer saturation bound (|dot|<=1152)
//      proves clip is identity -> integer-only inner loop (18 xor+popcll),
//      one f64 fma at end (f64 sum-order change ~1e-16, sign-stable).
//      Slow path kept verbatim for channels that could saturate.
//      (b) K4 fused into K3 via last-arrival per-image atomic counter
//      (store partials -> threadfence -> atomicAdd; 28th block finalizes
//      pool+FC for its n, identical f64 order). Counter zeroed in K2.
//      Saves K4 launch + gap; finalize overlaps K3 tail. K1/K2 unchanged.
// ---------------------------------------------------------------------------

// ws layout (bytes)
#define WP2_OFF    2048ull     // u64[128*9]       layer2 packed weights [co][tap]
#define WP3T_OFF   16384ull    // u64[18*256]      layer3 packed weights [tap*2+half][co]
#define WFP_OFF    65536ull    // u64[1000*4]      fc packed weights
#define PART_OFF   100352ull   // double[128]      alpha partials (t=1:w2,2:w3,3:wf)
#define CNT_OFF    101376ull   // u32[32]          per-image arrival counters (K3)
#define P1_OFF     102400ull   // u64[32*112*112]  layer1 out signs (bit=co)
#define P2_OFF     3313664ull  // u32[32*56*56*4]  layer2 out signs (quarters)
#define POOLP_OFF  4919296ull  // double[32*28*256] conv3 row-partial pool sums

// ---- K1: pack/alpha blocks 0..159 (dispatched FIRST, overlap conv wave);
//          conv blocks 160..1055: n=(bid-160)/28, 4 output rows each.
__global__ __launch_bounds__(256) void k1_conv1_pack(
    const float* __restrict__ x,  const float* __restrict__ w1, const float* __restrict__ b1,
    const float* __restrict__ w2, const float* __restrict__ w3, const float* __restrict__ wf,
    uint64_t* __restrict__ wp2, uint64_t* __restrict__ wp3t, uint64_t* __restrict__ wfp,
    double* __restrict__ part, uint64_t* __restrict__ p1)
{
    const int tid = threadIdx.x, lane = tid & 63, wid = tid >> 6, bid = blockIdx.x;
    if (bid >= 160) {
        __shared__ float4   xf4[1512];        // 27 segs x 56 float4 (24.2 KB)
        __shared__ uint32_t xb[216];          // 27 segs x 8 u32 sign-bit words
        __shared__ uint32_t xms[448];         // per-position 27-bit input masks
        __shared__ uint32_t wm[64];
        __shared__ double   a2s;
        const float* xf = (const float*)xf4;

        int cb = bid - 160;
        int n = cb / 28, hb = cb % 28;
        int ho0 = hb * 4;
        int hi0 = 2 * ho0 - 1;                // first staged input row (may be -1)

        // prelude (waves 0/1) overlapped with float4 staging below
        if (wid == 0) {                       // alpha1: coalesced + butterfly
            double s = 0.0;
            #pragma unroll
            for (int i = 0; i < 27; i++) s += fabs((double)w1[lane + i*64]);
            #pragma unroll
            for (int off = 1; off < 64; off <<= 1) s += __shfl_xor(s, off, 64);
            if (lane == 0) { double a = s / 1728.0; a2s = a * a; }
        } else if (wid == 1) {                // wm1 pack (27-bit masks)
            uint32_t m = 0;
            for (int t = 0; t < 27; t++) {
                int ci = t / 9, r = t % 9, kh = r / 3, kw = r % 3;
                if (w1[((lane*3 + ci)*3 + kh)*3 + kw] >= 0.f) m |= (1u << t);
            }
            wm[lane] = m;
        }
        // stage 27 row segments (seg = ci*9 + r, hi = hi0 + r), float4 coalesced
        const float4* xg = (const float4*)x;
        for (int i = tid; i < 1512; i += 256) {
            int seg = i / 56, f4 = i % 56;
            int ci = seg / 9, r = seg % 9;
            int hi = hi0 + r;
            float4 v = make_float4(0.f, 0.f, 0.f, 0.f);
            if ((unsigned)hi < 224u) v = xg[((n*3 + ci)*224 + hi)*56 + f4];
            xf4[i] = v;
        }
        __syncthreads();

        // per-lane channel threshold -> mismatch bounds (K2-style M-table).
        uint32_t wmr = wm[lane];
        int Mn, Ml;
        {
            double a2 = a2s, b = (double)b1[lane];
            int k = (int)ceil(-b / a2);
            k = max(-27, min(28, k));
            while (k > -27 && (a2 * (double)(k - 1) + b >= 0.0)) k--;
            while (k <= 27 && !(a2 * (double)k + b >= 0.0)) k++;
            int cntT  = __popc(wmr & 0x1C0E07u);   // kh==0 taps
            int cntL  = __popc(wmr & 0x1249249u);  // kw==0 taps
            int cntTL = __popc(wmr & 0x40201u);    // kh==0 && kw==0
            bool topw = (hb == 0 && wid == 0);     // wave owns output row hop=ho0+wid
            if (topw) {
                Mn = ((18 - k) >> 1) + 9 - cntT;               // top, interior col
                Ml = ((12 - k) >> 1) + cntL + 6 - cntT + cntTL; // top-left corner
            } else {
                Mn = (27 - k) >> 1;                            // interior
                Ml = ((18 - k) >> 1) + cntL;                   // left col
            }
        }

        // pack sign bits: thread t<189 owns u32 word j of seg (7 words = 224 cols)
        if (tid < 189) {
            int seg = tid / 7, j = tid % 7;
            uint32_t u = 0;
            #pragma unroll
            for (int k = 0; k < 32; k++) {
                int o = (k + tid) & 31;
                if (xf[seg*224 + j*32 + o] >= 0.f) u |= (1u << o);
            }
            xb[seg*8 + j] = u;
        } else if (tid < 216) {
            xb[(tid - 189)*8 + 7] = 0u;       // pad word (cols 224..255)
        }
        __syncthreads();

        // B1: build all 448 position masks into LDS (2 per thread)
        for (int pass = 0; pass < 2; pass++) {
            int s = tid + pass*256;
            if (s >= 448) break;
            int dho = s / 112, wo = s % 112;
            int c0 = 2*wo - 1;
            uint32_t xm = 0;
            if (wo > 0) {
                int w0 = c0 >> 5, sh = c0 & 31;
                #pragma unroll
                for (int ci = 0; ci < 3; ci++)
                    #pragma unroll
                    for (int kh = 0; kh < 3; kh++) {
                        int seg = ci*9 + 2*dho + kh;
                        uint64_t dw = (uint64_t)xb[seg*8 + w0]
                                    | ((uint64_t)xb[seg*8 + w0 + 1] << 32);
                        xm |= (uint32_t)((dw >> sh) & 7u) << (ci*9 + kh*3);
                    }
            } else {
                #pragma unroll
                for (int ci = 0; ci < 3; ci++)
                    #pragma unroll
                    for (int kh = 0; kh < 3; kh++) {
                        int seg = ci*9 + 2*dho + kh;
                        xm |= ((xb[seg*8] << 1) & 6u) << (ci*9 + kh*3);
                    }
            }
            xms[s] = xm;
        }
        __syncthreads();

        // B2: wave = output row (dho = wid), lane = channel; ballot is p1 word.
        {
            int hop = ho0 + wid;
            const uint32_t* xrow = &xms[wid*112];
            uint64_t r0 = 0, r1 = 0;
            {   // wo = 0 (left-col config)
                int mm = __popc(xrow[0] ^ wmr);
                uint64_t bal = __ballot(mm <= Ml);
                r0 = (lane == 0) ? bal : r0;
            }
            for (int wo = 1; wo < 64; wo++) {
                int mm = __popc(xrow[wo] ^ wmr);
                uint64_t bal = __ballot(mm <= Mn);
                r0 = (lane == wo) ? bal : r0;
            }
            for (int wo = 64; wo < 112; wo++) {
                int mm = __popc(xrow[wo] ^ wmr);
                uint64_t bal = __ballot(mm <= Mn);
                r1 = (lane == (wo - 64)) ? bal : r1;
            }
            uint64_t* __restrict__ prow = p1 + ((size_t)(n*112 + hop))*112;
            prow[lane] = r0;
            if (lane < 48) prow[64 + lane] = r1;
        }
    } else {
        int rel = bid;                        // 0..159 (dispatched first)
        if (rel < 96) {                        // alpha partials (R6-identical)
            __shared__ double sd[256];
            int t = rel >> 5, c = rel & 31;
            const float* w; int n;
            if (t == 0)      { w = w2; n = 128*64*9; }
            else if (t == 1) { w = w3; n = 256*128*9; }
            else             { w = wf; n = 1000*256; }
            int per = (n + 31) / 32;
            int lo = c * per, hi = min(n, lo + per);
            double s0 = 0.0, s1 = 0.0, s2 = 0.0, s3 = 0.0;
            int i = lo + tid;
            for (; i + 768 < hi; i += 1024) {
                s0 += fabs((double)w[i]);
                s1 += fabs((double)w[i + 256]);
                s2 += fabs((double)w[i + 512]);
                s3 += fabs((double)w[i + 768]);
            }
            for (; i < hi; i += 256) s0 += fabs((double)w[i]);
            sd[tid] = (s0 + s1) + (s2 + s3);
            __syncthreads();
            for (int off = 128; off > 0; off >>= 1) {
                if (tid < off) sd[tid] += sd[tid + off];
                __syncthreads();
            }
            if (tid == 0) part[(t + 1)*32 + c] = sd[0];
        }
        int gw = rel * 4 + wid;               // ballot packing over 640 waves
        const int nw = 640;
        for (int w = gw; w < 1152; w += nw) {
            int co = w / 9, tap = w % 9, kh = tap / 3, kw = tap % 3;
            uint64_t b = __ballot(w2[((co*64 + lane)*3 + kh)*3 + kw] >= 0.f);
            if (lane == 0) wp2[w] = b;
        }
        for (int w = gw; w < 4608; w += nw) {
            int co = w / 18, r = w % 18, tap = r / 2, half = r & 1;
            int kh = tap / 3, kw = tap % 3;
            uint64_t b = __ballot(w3[((co*128 + half*64 + lane)*3 + kh)*3 + kw] >= 0.f);
            if (lane == 0) wp3t[(tap*2 + half)*256 + co] = b;
        }
        for (int w = gw; w < 4000; w += nw) {
            int o = w >> 2, j = w & 3;
            uint64_t b = __ballot(wf[o*256 + j*64 + lane] >= 0.f);
            if (lane == 0) wfp[w] = b;
        }
    }
}

// ---- K2: conv2, 2 positions/lane, integer-threshold epilogue (R8). ----
//      Also zeroes the K3 arrival counters (block 0) before K3 launches.
__global__ __launch_bounds__(256) void k2_conv2(
    const uint64_t* __restrict__ p1, const float* __restrict__ b2,
    const double* __restrict__ part, const uint64_t* __restrict__ wp2g,
    uint32_t* __restrict__ p2, uint32_t* __restrict__ cnt)
{
    __shared__ uint64_t wp[1152];      // [co][tap]
    __shared__ uint64_t xs[1152];      // [tap][128 positions], zero-padded
    __shared__ int      M[128*4];      // [co][cfg] popcount bound
    const int tid = threadIdx.x, lane = tid & 63;

    if (blockIdx.x == 0 && tid < 32) cnt[tid] = 0;   // arm K3 last-arrival

    for (int i = tid; i < 1152; i += 256) wp[i] = wp2g[i];
    for (int i = tid; i < 1152; i += 256) {
        int t = i >> 7, pl = i & 127;
        int pos = blockIdx.x * 128 + pl;
        int wo = pos % 56, t1 = pos / 56;
        int ho = t1 % 56, n = t1 / 56;
        int kh = t / 3, kw = t % 3;
        int hi = 2*ho + kh - 1, wi = 2*wo + kw - 1;
        bool ok = ((unsigned)hi < 112u) && ((unsigned)wi < 112u);
        xs[i] = ok ? p1[(n*112 + hi)*112 + wi] : 0ull;
    }
    __syncthreads();
    if (tid < 128) {
        int co = tid;
        double s = 0.0;
        for (int j = 0; j < 32; j++) s += part[32 + j];
        double a = s / (double)(128*64*9);
        double a2 = a * a, b = (double)b2[co];
        int k = (int)ceil(-b / a2);
        k = max(-577, min(578, k));
        while (k > -577 && (a2 * (double)(k - 1) + b >= 0.0)) k--;
        while (k <= 577 && !(a2 * (double)k + b >= 0.0)) k++;
        uint32_t P[9];
        #pragma unroll
        for (int t = 0; t < 9; t++) P[t] = __popcll(wp[co*9 + t]);
        int cT = P[0] + P[1] + P[2];
        int cL = P[0] + P[3] + P[6];
        int cC = P[0];
        #pragma unroll
        for (int cfg = 0; cfg < 4; cfg++) {
            int isT = cfg & 1, isL = (cfg >> 1) & 1;
            int V = 9 - 3*isT - 3*isL + (isT & isL);
            int corr = isT*cT + isL*cL - (isT & isL)*cC;
            int dtab = 64*V + 2*corr;
            M[co*4 + cfg] = (dtab - k) >> 1;
        }
    }
    __syncthreads();

    int q = tid >> 6;
    int co0 = q * 32;
    int pos0 = blockIdx.x * 128 + lane;
    int pos1 = pos0 + 64;
    int wo0 = pos0 % 56, ho0 = (pos0 / 56) % 56;
    int wo1 = pos1 % 56, ho1 = (pos1 / 56) % 56;
    int cfg0 = (ho0 == 0 ? 1 : 0) | (wo0 == 0 ? 2 : 0);
    int cfg1 = (ho1 == 0 ? 1 : 0) | (wo1 == 0 ? 2 : 0);
    uint64_t xv0[9], xv1[9];
    #pragma unroll
    for (int t = 0; t < 9; t++) { xv0[t] = xs[t*128 + lane]; xv1[t] = xs[t*128 + 64 + lane]; }
    uint32_t bits0 = 0, bits1 = 0;
    for (int c = 0; c < 32; c++) {
        int co = co0 + c;
        int mm0 = 0, mm1 = 0;
        #pragma unroll
        for (int t = 0; t < 9; t++) {
            uint64_t w = wp[co*9 + t];
            mm0 += __popcll(xv0[t] ^ w);
            mm1 += __popcll(xv1[t] ^ w);
        }
        if (mm0 <= M[co*4 + cfg0]) bits0 |= (1u << c);
        if (mm1 <= M[co*4 + cfg1]) bits1 |= (1u << c);
    }
    p2[pos0*4 + q] = bits0;
    p2[pos1*4 + q] = bits1;
}

// ---- K3: conv3 + pool row partials + last-arrival pool-finalize/FC.
//      block=(n,ho), thread=co. Fast path: integer-only inner loop when the
//      clip is provably identity (|dot|<=1152 bound); slow path verbatim R8.
__global__ __launch_bounds__(256) void k3_conv3poolfc(
    const uint64_t* __restrict__ p2, const float* __restrict__ b3,
    const double* __restrict__ part, const uint64_t* __restrict__ wp3t,
    double* __restrict__ partial, uint32_t* __restrict__ cnt,
    const uint64_t* __restrict__ wfp, const float* __restrict__ bf,
    float* __restrict__ out)
{
    __shared__ uint64_t xs[28*18];
    __shared__ uint64_t spl[4];
    __shared__ int lastf;
    const int tid = threadIdx.x;
    int n = blockIdx.x / 28, ho = blockIdx.x % 28;

    double s = 0.0;
    for (int j = 0; j < 32; j++) s += part[64 + j];
    double a = s / (double)(256*128*9);
    double a2 = a * a;

    uint64_t w[18];
    #pragma unroll
    for (int i = 0; i < 18; i++) w[i] = wp3t[i*256 + tid];
    uint32_t P[9];
    #pragma unroll
    for (int t = 0; t < 9; t++) P[t] = __popcll(w[2*t]) + __popcll(w[2*t+1]);

    for (int i = tid; i < 504; i += 256) {
        int wo = i / 18, r = i % 18;
        int tap = r / 2, half = r % 2;
        int kh = tap / 3, kw = tap % 3;
        int hi = 2*ho + kh - 1, wi = 2*wo + kw - 1;
        bool ok = ((unsigned)hi < 56u) && ((unsigned)wi < 56u);
        xs[i] = ok ? p2[(size_t)((n*56 + hi)*56 + wi)*2 + half] : 0ull;
    }
    __syncthreads();

    bool htop = (ho == 0);
    int rv = htop ? 2 : 3;
    double bc = (double)b3[tid];
    int cT = P[0] + P[1] + P[2];
    int cL = P[0] + P[3] + P[6];
    double sum;
    // clip-identity bound: |dot| <= 1152 for every position/cfg
    bool fastok = (a2 * 1152.0 + bc <= 1.0) && (bc - a2 * 1152.0 >= -1.0);
    if (fastok) {
        int mm0 = 0, mmacc = 0;
        for (int wo = 0; wo < 28; wo++) {
            int mm = 0;
            #pragma unroll
            for (int t = 0; t < 18; t++)
                mm += __popcll(xs[wo*18 + t] ^ w[t]);
            if (wo == 0) mm0 = mm; else mmacc += mm;
        }
        int corr_n = htop ? cT : 0;                       // interior-col corr
        int corr_l = corr_n + cL - (htop ? P[0] : 0);     // wo==0 corr
        int dotsum = 27*(128*rv*3 + 2*corr_n)
                   + (128*rv*2 + 2*corr_l)
                   - 2*(mmacc + mm0);
        sum = a2 * (double)dotsum + 28.0 * bc;
    } else {
        sum = 0.0;
        for (int wo = 0; wo < 28; wo++) {
            int mm = 0;
            #pragma unroll
            for (int t = 0; t < 18; t++)
                mm += __popcll(xs[wo*18 + t] ^ w[t]);
            bool wl = (wo == 0);
            int cv = wl ? 2 : 3;
            int corr = 0;
            if (htop) corr += cT;
            if (wl)   corr += cL;
            if (htop && wl) corr -= P[0];
            int dot = 128*(rv*cv) - 2*mm + 2*corr;
            double h = a2 * (double)dot + bc;
            h = fmin(fmax(h, -1.0), 1.0);
            sum += h;
        }
    }
    partial[(size_t)(n*28 + ho)*256 + tid] = sum;

    // last-arrival handoff (device-scope: release fence + atomic)
    __threadfence();
    __syncthreads();
    if (tid == 0) {
        int old = atomicAdd(&cnt[n], 1u);
        lastf = (old == 27) ? 1 : 0;
    }
    __syncthreads();
    if (!lastf) return;
    __threadfence();                       // acquire: see all 28 row partials

    // former K4 for this n (identical f64 ho-order sum)
    const int lane = tid & 63;
    double ps = 0.0;
    for (int c = 0; c < 28; c++) ps += partial[(size_t)(n*28 + c)*256 + tid];
    uint64_t bal = __ballot((ps / 784.0) >= 0.0);
    if (lane == 0) spl[tid >> 6] = bal;

    double sa = 0.0;
    for (int j = 0; j < 32; j++) sa += part[96 + j];
    double af = sa / (double)(1000*256);
    double aa = af * af;
    __syncthreads();
    uint64_t t0 = spl[0], t1 = spl[1], t2 = spl[2], t3 = spl[3];
    for (int o = tid; o < 1000; o += 256) {
        int m = __popcll(t0 ^ wfp[o*4]) + __popcll(t1 ^ wfp[o*4+1])
              + __popcll(t2 ^ wfp[o*4+2]) + __popcll(t3 ^ wfp[o*4+3]);
        out[n*1000 + o] = (float)(aa * (double)(256 - 2*m) + (double)bf[o]);
    }
}

extern "C" void kernel_launch(void* const* d_in, const int* in_sizes, int n_in,
                              void* d_out, int out_size, void* d_ws, size_t ws_size,
                              hipStream_t stream) {
    const float* x  = (const float*)d_in[0];
    const float* w1 = (const float*)d_in[1];
    const float* b1 = (const float*)d_in[2];
    const float* w2 = (const float*)d_in[3];
    const float* b2 = (const float*)d_in[4];
    const float* w3 = (const float*)d_in[5];
    const float* b3 = (const float*)d_in[6];
    const float* wf = (const float*)d_in[7];
    const float* bf = (const float*)d_in[8];

    char* ws = (char*)d_ws;
    uint64_t* wp2    = (uint64_t*)(ws + WP2_OFF);
    uint64_t* wp3t   = (uint64_t*)(ws + WP3T_OFF);
    uint64_t* wfp    = (uint64_t*)(ws + WFP_OFF);
    double*   part   = (double*)  (ws + PART_OFF);
    uint32_t* cnt    = (uint32_t*)(ws + CNT_OFF);
    uint64_t* p1     = (uint64_t*)(ws + P1_OFF);
    uint32_t* p2     = (uint32_t*)(ws + P2_OFF);
    double*   poolp  = (double*)  (ws + POOLP_OFF);
    float*    out    = (float*)   d_out;

    hipLaunchKernelGGL(k1_conv1_pack, dim3(1056), dim3(256), 0, stream,
                       x, w1, b1, w2, w3, wf, wp2, wp3t, wfp, part, p1);
    hipLaunchKernelGGL(k2_conv2,      dim3(784),  dim3(256), 0, stream,
                       p1, b2, part, wp2, p2, cnt);
    hipLaunchKernelGGL(k3_conv3poolfc, dim3(896), dim3(256), 0, stream,
                       (const uint64_t*)p2, b3, part, wp3t, poolp, cnt,
                       wfp, bf, out);
}

// Round 4
// 141.697 us; speedup vs baseline: 1.4974x; 1.4974x over previous
//
#include <hip/hip_runtime.h>
#include <stdint.h>
#include <math.h>

// ---------------------------------------------------------------------------
// XNOR-Net forward: 3 binarized stride-2 convs + global avg pool + binary FC.
// Exact integer popcount dots; sign decisions via exact integer thresholds.
// Ledger: ~85us fixed harness work (268MB ws re-poison fills at ~43us each,
// 78% HBM peak = their roofline); fill variance => run noise ~±5us.
// R9=142.8, R10=151.0 (FAILED: lane0 scalar stores), R11=144.5 (recovered),
// R12=212.2 (FAILED: last-arrival fusion; __threadfence at block scope =>
// cross-XCD L2 writeback/invalidate serializes chip: k3 7us->107us,
// VALUBusy 12%, HBM 0.5%. NEVER fence on the per-block path on gfx950).
// R13: revert to R11 4-kernel structure; keep R12's K3 integer fast-path
// (clip-identity proven by |dot|<=1152 bound; hardware-validated absmax=0),
// now wave-uniform via __all() so mixed waves never pay both loops.
// ---------------------------------------------------------------------------

// ws layout (bytes)
#define WP2_OFF    2048ull     // u64[128*9]       layer2 packed weights [co][tap]
#define WP3T_OFF   16384ull    // u64[18*256]      layer3 packed weights [tap*2+half][co]
#define WFP_OFF    65536ull    // u64[1000*4]      fc packed weights
#define PART_OFF   100352ull   // double[128]      alpha partials (t=1:w2,2:w3,3:wf)
#define P1_OFF     102400ull   // u64[32*112*112]  layer1 out signs (bit=co)
#define P2_OFF     3313664ull  // u32[32*56*56*4]  layer2 out signs (quarters)
#define POOLP_OFF  4919296ull  // double[32*28*256] conv3 row-partial pool sums

// ---- K1: pack/alpha blocks 0..159 (dispatched FIRST, overlap conv wave);
//          conv blocks 160..1055: n=(bid-160)/28, 4 output rows each.
__global__ __launch_bounds__(256) void k1_conv1_pack(
    const float* __restrict__ x,  const float* __restrict__ w1, const float* __restrict__ b1,
    const float* __restrict__ w2, const float* __restrict__ w3, const float* __restrict__ wf,
    uint64_t* __restrict__ wp2, uint64_t* __restrict__ wp3t, uint64_t* __restrict__ wfp,
    double* __restrict__ part, uint64_t* __restrict__ p1)
{
    const int tid = threadIdx.x, lane = tid & 63, wid = tid >> 6, bid = blockIdx.x;
    if (bid >= 160) {
        __shared__ float4   xf4[1512];        // 27 segs x 56 float4 (24.2 KB)
        __shared__ uint32_t xb[216];          // 27 segs x 8 u32 sign-bit words
        __shared__ uint32_t xms[448];         // per-position 27-bit input masks
        __shared__ uint32_t wm[64];
        __shared__ double   a2s;
        const float* xf = (const float*)xf4;

        int cb = bid - 160;
        int n = cb / 28, hb = cb % 28;
        int ho0 = hb * 4;
        int hi0 = 2 * ho0 - 1;                // first staged input row (may be -1)

        // prelude (waves 0/1) overlapped with float4 staging below
        if (wid == 0) {                       // alpha1: coalesced + butterfly
            double s = 0.0;
            #pragma unroll
            for (int i = 0; i < 27; i++) s += fabs((double)w1[lane + i*64]);
            #pragma unroll
            for (int off = 1; off < 64; off <<= 1) s += __shfl_xor(s, off, 64);
            if (lane == 0) { double a = s / 1728.0; a2s = a * a; }
        } else if (wid == 1) {                // wm1 pack (27-bit masks)
            uint32_t m = 0;
            for (int t = 0; t < 27; t++) {
                int ci = t / 9, r = t % 9, kh = r / 3, kw = r % 3;
                if (w1[((lane*3 + ci)*3 + kh)*3 + kw] >= 0.f) m |= (1u << t);
            }
            wm[lane] = m;
        }
        // stage 27 row segments (seg = ci*9 + r, hi = hi0 + r), float4 coalesced
        const float4* xg = (const float4*)x;
        for (int i = tid; i < 1512; i += 256) {
            int seg = i / 56, f4 = i % 56;
            int ci = seg / 9, r = seg % 9;
            int hi = hi0 + r;
            float4 v = make_float4(0.f, 0.f, 0.f, 0.f);
            if ((unsigned)hi < 224u) v = xg[((n*3 + ci)*224 + hi)*56 + f4];
            xf4[i] = v;
        }
        __syncthreads();

        // per-lane channel threshold -> mismatch bounds (K2-style M-table).
        uint32_t wmr = wm[lane];
        int Mn, Ml;
        {
            double a2 = a2s, b = (double)b1[lane];
            int k = (int)ceil(-b / a2);
            k = max(-27, min(28, k));
            while (k > -27 && (a2 * (double)(k - 1) + b >= 0.0)) k--;
            while (k <= 27 && !(a2 * (double)k + b >= 0.0)) k++;
            int cntT  = __popc(wmr & 0x1C0E07u);   // kh==0 taps
            int cntL  = __popc(wmr & 0x1249249u);  // kw==0 taps
            int cntTL = __popc(wmr & 0x40201u);    // kh==0 && kw==0
            bool topw = (hb == 0 && wid == 0);     // wave owns output row hop=ho0+wid
            if (topw) {
                Mn = ((18 - k) >> 1) + 9 - cntT;               // top, interior col
                Ml = ((12 - k) >> 1) + cntL + 6 - cntT + cntTL; // top-left corner
            } else {
                Mn = (27 - k) >> 1;                            // interior
                Ml = ((18 - k) >> 1) + cntL;                   // left col
            }
        }

        // pack sign bits: thread t<189 owns u32 word j of seg (7 words = 224 cols)
        if (tid < 189) {
            int seg = tid / 7, j = tid % 7;
            uint32_t u = 0;
            #pragma unroll
            for (int k = 0; k < 32; k++) {
                int o = (k + tid) & 31;
                if (xf[seg*224 + j*32 + o] >= 0.f) u |= (1u << o);
            }
            xb[seg*8 + j] = u;
        } else if (tid < 216) {
            xb[(tid - 189)*8 + 7] = 0u;       // pad word (cols 224..255)
        }
        __syncthreads();

        // B1: build all 448 position masks into LDS (2 per thread)
        for (int pass = 0; pass < 2; pass++) {
            int s = tid + pass*256;
            if (s >= 448) break;
            int dho = s / 112, wo = s % 112;
            int c0 = 2*wo - 1;
            uint32_t xm = 0;
            if (wo > 0) {
                int w0 = c0 >> 5, sh = c0 & 31;
                #pragma unroll
                for (int ci = 0; ci < 3; ci++)
                    #pragma unroll
                    for (int kh = 0; kh < 3; kh++) {
                        int seg = ci*9 + 2*dho + kh;
                        uint64_t dw = (uint64_t)xb[seg*8 + w0]
                                    | ((uint64_t)xb[seg*8 + w0 + 1] << 32);
                        xm |= (uint32_t)((dw >> sh) & 7u) << (ci*9 + kh*3);
                    }
            } else {
                #pragma unroll
                for (int ci = 0; ci < 3; ci++)
                    #pragma unroll
                    for (int kh = 0; kh < 3; kh++) {
                        int seg = ci*9 + 2*dho + kh;
                        xm |= ((xb[seg*8] << 1) & 6u) << (ci*9 + kh*3);
                    }
            }
            xms[s] = xm;
        }
        __syncthreads();

        // B2: wave = output row (dho = wid), lane = channel; ballot is p1 word.
        {
            int hop = ho0 + wid;
            const uint32_t* xrow = &xms[wid*112];
            uint64_t r0 = 0, r1 = 0;
            {   // wo = 0 (left-col config)
                int mm = __popc(xrow[0] ^ wmr);
                uint64_t bal = __ballot(mm <= Ml);
                r0 = (lane == 0) ? bal : r0;
            }
            for (int wo = 1; wo < 64; wo++) {
                int mm = __popc(xrow[wo] ^ wmr);
                uint64_t bal = __ballot(mm <= Mn);
                r0 = (lane == wo) ? bal : r0;
            }
            for (int wo = 64; wo < 112; wo++) {
                int mm = __popc(xrow[wo] ^ wmr);
                uint64_t bal = __ballot(mm <= Mn);
                r1 = (lane == (wo - 64)) ? bal : r1;
            }
            uint64_t* __restrict__ prow = p1 + ((size_t)(n*112 + hop))*112;
            prow[lane] = r0;
            if (lane < 48) prow[64 + lane] = r1;
        }
    } else {
        int rel = bid;                        // 0..159 (dispatched first)
        if (rel < 96) {                        // alpha partials (R6-identical)
            __shared__ double sd[256];
            int t = rel >> 5, c = rel & 31;
            const float* w; int n;
            if (t == 0)      { w = w2; n = 128*64*9; }
            else if (t == 1) { w = w3; n = 256*128*9; }
            else             { w = wf; n = 1000*256; }
            int per = (n + 31) / 32;
            int lo = c * per, hi = min(n, lo + per);
            double s0 = 0.0, s1 = 0.0, s2 = 0.0, s3 = 0.0;
            int i = lo + tid;
            for (; i + 768 < hi; i += 1024) {
                s0 += fabs((double)w[i]);
                s1 += fabs((double)w[i + 256]);
                s2 += fabs((double)w[i + 512]);
                s3 += fabs((double)w[i + 768]);
            }
            for (; i < hi; i += 256) s0 += fabs((double)w[i]);
            sd[tid] = (s0 + s1) + (s2 + s3);
            __syncthreads();
            for (int off = 128; off > 0; off >>= 1) {
                if (tid < off) sd[tid] += sd[tid + off];
                __syncthreads();
            }
            if (tid == 0) part[(t + 1)*32 + c] = sd[0];
        }
        int gw = rel * 4 + wid;               // ballot packing over 640 waves
        const int nw = 640;
        for (int w = gw; w < 1152; w += nw) {
            int co = w / 9, tap = w % 9, kh = tap / 3, kw = tap % 3;
            uint64_t b = __ballot(w2[((co*64 + lane)*3 + kh)*3 + kw] >= 0.f);
            if (lane == 0) wp2[w] = b;
        }
        for (int w = gw; w < 4608; w += nw) {
            int co = w / 18, r = w % 18, tap = r / 2, half = r & 1;
            int kh = tap / 3, kw = tap % 3;
            uint64_t b = __ballot(w3[((co*128 + half*64 + lane)*3 + kh)*3 + kw] >= 0.f);
            if (lane == 0) wp3t[(tap*2 + half)*256 + co] = b;
        }
        for (int w = gw; w < 4000; w += nw) {
            int o = w >> 2, j = w & 3;
            uint64_t b = __ballot(wf[o*256 + j*64 + lane] >= 0.f);
            if (lane == 0) wfp[w] = b;
        }
    }
}

// ---- K2: conv2, 2 positions/lane, integer-threshold epilogue (R8). ----
__global__ __launch_bounds__(256) void k2_conv2(
    const uint64_t* __restrict__ p1, const float* __restrict__ b2,
    const double* __restrict__ part, const uint64_t* __restrict__ wp2g,
    uint32_t* __restrict__ p2)
{
    __shared__ uint64_t wp[1152];      // [co][tap]
    __shared__ uint64_t xs[1152];      // [tap][128 positions], zero-padded
    __shared__ int      M[128*4];      // [co][cfg] popcount bound
    const int tid = threadIdx.x, lane = tid & 63;

    for (int i = tid; i < 1152; i += 256) wp[i] = wp2g[i];
    for (int i = tid; i < 1152; i += 256) {
        int t = i >> 7, pl = i & 127;
        int pos = blockIdx.x * 128 + pl;
        int wo = pos % 56, t1 = pos / 56;
        int ho = t1 % 56, n = t1 / 56;
        int kh = t / 3, kw = t % 3;
        int hi = 2*ho + kh - 1, wi = 2*wo + kw - 1;
        bool ok = ((unsigned)hi < 112u) && ((unsigned)wi < 112u);
        xs[i] = ok ? p1[(n*112 + hi)*112 + wi] : 0ull;
    }
    __syncthreads();
    if (tid < 128) {
        int co = tid;
        double s = 0.0;
        for (int j = 0; j < 32; j++) s += part[32 + j];
        double a = s / (double)(128*64*9);
        double a2 = a * a, b = (double)b2[co];
        int k = (int)ceil(-b / a2);
        k = max(-577, min(578, k));
        while (k > -577 && (a2 * (double)(k - 1) + b >= 0.0)) k--;
        while (k <= 577 && !(a2 * (double)k + b >= 0.0)) k++;
        uint32_t P[9];
        #pragma unroll
        for (int t = 0; t < 9; t++) P[t] = __popcll(wp[co*9 + t]);
        int cT = P[0] + P[1] + P[2];
        int cL = P[0] + P[3] + P[6];
        int cC = P[0];
        #pragma unroll
        for (int cfg = 0; cfg < 4; cfg++) {
            int isT = cfg & 1, isL = (cfg >> 1) & 1;
            int V = 9 - 3*isT - 3*isL + (isT & isL);
            int corr = isT*cT + isL*cL - (isT & isL)*cC;
            int dtab = 64*V + 2*corr;
            M[co*4 + cfg] = (dtab - k) >> 1;
        }
    }
    __syncthreads();

    int q = tid >> 6;
    int co0 = q * 32;
    int pos0 = blockIdx.x * 128 + lane;
    int pos1 = pos0 + 64;
    int wo0 = pos0 % 56, ho0 = (pos0 / 56) % 56;
    int wo1 = pos1 % 56, ho1 = (pos1 / 56) % 56;
    int cfg0 = (ho0 == 0 ? 1 : 0) | (wo0 == 0 ? 2 : 0);
    int cfg1 = (ho1 == 0 ? 1 : 0) | (wo1 == 0 ? 2 : 0);
    uint64_t xv0[9], xv1[9];
    #pragma unroll
    for (int t = 0; t < 9; t++) { xv0[t] = xs[t*128 + lane]; xv1[t] = xs[t*128 + 64 + lane]; }
    uint32_t bits0 = 0, bits1 = 0;
    for (int c = 0; c < 32; c++) {
        int co = co0 + c;
        int mm0 = 0, mm1 = 0;
        #pragma unroll
        for (int t = 0; t < 9; t++) {
            uint64_t w = wp[co*9 + t];
            mm0 += __popcll(xv0[t] ^ w);
            mm1 += __popcll(xv1[t] ^ w);
        }
        if (mm0 <= M[co*4 + cfg0]) bits0 |= (1u << c);
        if (mm1 <= M[co*4 + cfg1]) bits1 |= (1u << c);
    }
    p2[pos0*4 + q] = bits0;
    p2[pos1*4 + q] = bits1;
}

// ---- K3: conv3 + pool row partials. block=(n,ho), thread=co.
//      Wave-uniform integer fast path when clip is provably identity
//      (|dot| <= 1152 bound); slow path verbatim R8 otherwise.
__global__ __launch_bounds__(256) void k3_conv3pool(
    const uint64_t* __restrict__ p2, const float* __restrict__ b3,
    const double* __restrict__ part, const uint64_t* __restrict__ wp3t,
    double* __restrict__ partial)
{
    __shared__ uint64_t xs[28*18];
    const int tid = threadIdx.x;
    int n = blockIdx.x / 28, ho = blockIdx.x % 28;

    double s = 0.0;
    for (int j = 0; j < 32; j++) s += part[64 + j];
    double a = s / (double)(256*128*9);
    double a2 = a * a;

    uint64_t w[18];
    #pragma unroll
    for (int i = 0; i < 18; i++) w[i] = wp3t[i*256 + tid];
    uint32_t P[9];
    #pragma unroll
    for (int t = 0; t < 9; t++) P[t] = __popcll(w[2*t]) + __popcll(w[2*t+1]);

    for (int i = tid; i < 504; i += 256) {
        int wo = i / 18, r = i % 18;
        int tap = r / 2, half = r % 2;
        int kh = tap / 3, kw = tap % 3;
        int hi = 2*ho + kh - 1, wi = 2*wo + kw - 1;
        bool ok = ((unsigned)hi < 56u) && ((unsigned)wi < 56u);
        xs[i] = ok ? p2[(size_t)((n*56 + hi)*56 + wi)*2 + half] : 0ull;
    }
    __syncthreads();

    bool htop = (ho == 0);
    int rv = htop ? 2 : 3;
    double bc = (double)b3[tid];
    int cT = P[0] + P[1] + P[2];
    int cL = P[0] + P[3] + P[6];
    double sum;
    // clip-identity bound: |dot| <= 1152 for every position/cfg
    bool fastok = (a2 * 1152.0 + bc <= 1.0) && (bc - a2 * 1152.0 >= -1.0);
    if (__all(fastok)) {
        int mm0 = 0, mmacc = 0;
        for (int wo = 0; wo < 28; wo++) {
            int mm = 0;
            #pragma unroll
            for (int t = 0; t < 18; t++)
                mm += __popcll(xs[wo*18 + t] ^ w[t]);
            if (wo == 0) mm0 = mm; else mmacc += mm;
        }
        int corr_n = htop ? cT : 0;                       // interior-col corr
        int corr_l = corr_n + cL - (htop ? P[0] : 0);     // wo==0 corr
        int dotsum = 27*(128*rv*3 + 2*corr_n)
                   + (128*rv*2 + 2*corr_l)
                   - 2*(mmacc + mm0);
        sum = a2 * (double)dotsum + 28.0 * bc;
    } else {
        sum = 0.0;
        for (int wo = 0; wo < 28; wo++) {
            int mm = 0;
            #pragma unroll
            for (int t = 0; t < 18; t++)
                mm += __popcll(xs[wo*18 + t] ^ w[t]);
            bool wl = (wo == 0);
            int cv = wl ? 2 : 3;
            int corr = 0;
            if (htop) corr += cT;
            if (wl)   corr += cL;
            if (htop && wl) corr -= P[0];
            int dot = 128*(rv*cv) - 2*mm + 2*corr;
            double h = a2 * (double)dot + bc;
            h = fmin(fmax(h, -1.0), 1.0);
            sum += h;
        }
    }
    partial[(size_t)(n*28 + ho)*256 + tid] = sum;
}

// ---- K4: pool finalize (ho-order sum) + FC, block = image n ----
__global__ __launch_bounds__(256) void k4_poolfc(
    const double* __restrict__ partial, const uint64_t* __restrict__ wfp,
    const float* __restrict__ bf, const double* __restrict__ part,
    float* __restrict__ out)
{
    __shared__ uint64_t spl[4];
    const int tid = threadIdx.x, lane = tid & 63;
    int n = blockIdx.x;
    double s = 0.0;
    for (int c = 0; c < 28; c++) s += partial[(size_t)(n*28 + c)*256 + tid];
    uint64_t bal = __ballot((s / 784.0) >= 0.0);
    if (lane == 0) spl[tid >> 6] = bal;

    double sa = 0.0;
    for (int j = 0; j < 32; j++) sa += part[96 + j];
    double a = sa / (double)(1000*256);
    double aa = a * a;
    __syncthreads();
    uint64_t s0 = spl[0], s1 = spl[1], s2 = spl[2], s3 = spl[3];
    for (int o = tid; o < 1000; o += 256) {
        int m = __popcll(s0 ^ wfp[o*4]) + __popcll(s1 ^ wfp[o*4+1])
              + __popcll(s2 ^ wfp[o*4+2]) + __popcll(s3 ^ wfp[o*4+3]);
        out[n*1000 + o] = (float)(aa * (double)(256 - 2*m) + (double)bf[o]);
    }
}

extern "C" void kernel_launch(void* const* d_in, const int* in_sizes, int n_in,
                              void* d_out, int out_size, void* d_ws, size_t ws_size,
                              hipStream_t stream) {
    const float* x  = (const float*)d_in[0];
    const float* w1 = (const float*)d_in[1];
    const float* b1 = (const float*)d_in[2];
    const float* w2 = (const float*)d_in[3];
    const float* b2 = (const float*)d_in[4];
    const float* w3 = (const float*)d_in[5];
    const float* b3 = (const float*)d_in[6];
    const float* wf = (const float*)d_in[7];
    const float* bf = (const float*)d_in[8];

    char* ws = (char*)d_ws;
    uint64_t* wp2    = (uint64_t*)(ws + WP2_OFF);
    uint64_t* wp3t   = (uint64_t*)(ws + WP3T_OFF);
    uint64_t* wfp    = (uint64_t*)(ws + WFP_OFF);
    double*   part   = (double*)  (ws + PART_OFF);
    uint64_t* p1     = (uint64_t*)(ws + P1_OFF);
    uint32_t* p2     = (uint32_t*)(ws + P2_OFF);
    double*   poolp  = (double*)  (ws + POOLP_OFF);
    float*    out    = (float*)   d_out;

    hipLaunchKernelGGL(k1_conv1_pack, dim3(1056), dim3(256), 0, stream,
                       x, w1, b1, w2, w3, wf, wp2, wp3t, wfp, part, p1);
    hipLaunchKernelGGL(k2_conv2,      dim3(784),  dim3(256), 0, stream,
                       p1, b2, part, wp2, p2);
    hipLaunchKernelGGL(k3_conv3pool,  dim3(896),  dim3(256), 0, stream,
                       (const uint64_t*)p2, b3, part, wp3t, poolp);
    hipLaunchKernelGGL(k4_poolfc,     dim3(32),   dim3(256), 0, stream,
                       poolp, wfp, bf, part, out);
}